// Round 5
// baseline (925.555 us; speedup 1.0000x reference)
//
#include <hip/hip_runtime.h>

// Sparse UNet, fp16, phase-per-XCD L2-resident gather version.
//  - every gather table is an 8-channel fp16 phase array (16B rows, 1.92MB/stream)
//  - grid maps (stream, phase) -> XCD via bid%8 so each XCD's random gathers
//    touch only ONE 1.92MB sub-table (48% of its 4MB L2)
//  - conv2/conv3 write fp16 phase partials; combine kernel sums phases,
//    writes pre-BN rows, and computes BN stat partials
//  - nt stores on streaming outputs (don't evict gather tables from L2)

#define DEVI __device__ __forceinline__

typedef _Float16 h2 __attribute__((ext_vector_type(2)));
typedef unsigned u4 __attribute__((ext_vector_type(4)));

constexpr int KNBR = 27;

DEVI h2 bch2(unsigned u) { return __builtin_bit_cast(h2, u); }
DEVI unsigned pkh2(float a, float b) {
    h2 v; v.x = (_Float16)a; v.y = (_Float16)b;
    return __builtin_bit_cast(unsigned, v);
}
DEVI float bnr(float x, float sc, float sh) {
    float y = fmaf(x, sc, sh);
    return y > 0.f ? y : 0.f;
}

// ---------------- prep ----------------

// b0: W1 [k][6][16] -> [k][16][8]
// b1: W2 [k][16][32] -> [ph:2][k][32][8]
// b2: W3 [k][32][16] -> [ph:4][k][16][8]
// b3: zero bsum
__global__ __launch_bounds__(256)
void prep_weights_kernel(const float* __restrict__ W1, const float* __restrict__ W2,
                         const float* __restrict__ W3,
                         _Float16* __restrict__ w1t, _Float16* __restrict__ w2t,
                         _Float16* __restrict__ w3t,
                         float* __restrict__ bsum, int nb)
{
    const int b = blockIdx.x;
    if (b == 3) {
        for (int i = threadIdx.x; i < nb; i += 256) bsum[i] = 0.f;
        return;
    }
    if (b == 0) {
        for (int i = threadIdx.x; i < KNBR * 16 * 8; i += 256) {
            const int c = i % 8, d = (i / 8) % 16, k = i / 128;
            w1t[i] = (_Float16)((c < 6) ? W1[(k * 6 + c) * 16 + d] : 0.f);
        }
    } else if (b == 1) {
        for (int i = threadIdx.x; i < 2 * KNBR * 32 * 8; i += 256) {
            const int c = i % 8, d = (i / 8) % 32, k = (i / 256) % KNBR, ph = i / (256 * KNBR);
            w2t[i] = (_Float16)W2[(k * 16 + ph * 8 + c) * 32 + d];
        }
    } else {
        for (int i = threadIdx.x; i < 4 * KNBR * 16 * 8; i += 256) {
            const int c = i % 8, d = (i / 8) % 16, k = (i / 128) % KNBR, ph = i / (128 * KNBR);
            w3t[i] = (_Float16)W3[(k * 32 + ph * 8 + c) * 16 + d];
        }
    }
}

// fp32 [N][6] -> fp16 [s][(N+1)][8] (pad channels, zero row N)
__global__ __launch_bounds__(256)
void prep_feats_kernel(const float* __restrict__ f0, const float* __restrict__ f1,
                       _Float16* __restrict__ o, int N)
{
    const int s = blockIdx.y;
    const float* __restrict__ f = s ? f1 : f0;
    _Float16* __restrict__ out = o + (size_t)s * (N + 1) * 8;
    const int n = blockIdx.x * 256 + threadIdx.x;
    if (n < N) {
        const float2* r = (const float2*)(f + (size_t)n * 6);
        float2 a = r[0], b = r[1], c = r[2];
        u4 w;
        w.x = pkh2(a.x, a.y);
        w.y = pkh2(b.x, b.y);
        w.z = pkh2(c.x, c.y);
        w.w = 0u;
        ((u4*)out)[n] = w;
    } else if (n == N) {
        ((u4*)out)[n] = (u4){0u, 0u, 0u, 0u};
    }
}

// ---------------- conv1 (phase-less, stats epilogue) ----------------

__global__ __launch_bounds__(256)
void conv1_kernel(const _Float16* __restrict__ feats,   // [s][(N+1)][8]
                  const int* __restrict__ nb0, const int* __restrict__ nb1,
                  const _Float16* __restrict__ Wt,      // [27][16][8]
                  _Float16* __restrict__ outp,          // [s][(N+1)][16]
                  float* __restrict__ partials, int N, int B)
{
    const int bid = blockIdx.x;
    const int s = bid & 1;                 // XCD parity partition
    const int vb = bid >> 1;
    const int tid = threadIdx.x;

    __shared__ __align__(16) _Float16 wl[KNBR * 16 * 8];
    __shared__ float sred[4][64];
    for (int i = tid; i < KNBR * 16; i += 256)
        ((u4*)wl)[i] = ((const u4*)Wt)[i];
    __syncthreads();
    const u4* wp = (const u4*)wl;

    const size_t stride = (size_t)N + 1;
    const _Float16* __restrict__ fs = feats + (size_t)s * stride * 8;
    const int* __restrict__ nbr = s ? nb1 : nb0;
    const int n = vb * 256 + tid;
    const bool act = n < N;

    float acc[16];
    #pragma unroll
    for (int d = 0; d < 16; ++d) acc[d] = 0.f;

    int idx = act ? nbr[(size_t)n * KNBR] : N;
    u4 g = *(const u4*)(fs + (size_t)idx * 8);
    for (int k = 0; k < KNBR; ++k) {
        const int idn = (act && k + 1 < KNBR) ? nbr[(size_t)n * KNBR + k + 1] : idx;
        const u4 gn = *(const u4*)(fs + (size_t)idn * 8);
        #pragma unroll
        for (int d = 0; d < 16; ++d) {
            const u4 wv = wp[k * 16 + d];
            acc[d] = __builtin_amdgcn_fdot2(bch2(g.x), bch2(wv.x), acc[d], false);
            acc[d] = __builtin_amdgcn_fdot2(bch2(g.y), bch2(wv.y), acc[d], false);
            acc[d] = __builtin_amdgcn_fdot2(bch2(g.z), bch2(wv.z), acc[d], false);
            acc[d] = __builtin_amdgcn_fdot2(bch2(g.w), bch2(wv.w), acc[d], false);
        }
        g = gn; idx = idn;
    }

    if (act) {
        u4* orow = (u4*)(outp + ((size_t)s * stride + n) * 16);
        u4 v0 = {pkh2(acc[0], acc[1]), pkh2(acc[2], acc[3]), pkh2(acc[4], acc[5]), pkh2(acc[6], acc[7])};
        u4 v1 = {pkh2(acc[8], acc[9]), pkh2(acc[10], acc[11]), pkh2(acc[12], acc[13]), pkh2(acc[14], acc[15])};
        __builtin_nontemporal_store(v0, orow + 0);
        __builtin_nontemporal_store(v1, orow + 1);
    }

    float ts[16], tq[16];
    #pragma unroll
    for (int d = 0; d < 16; ++d) { ts[d] = acc[d]; tq[d] = acc[d] * acc[d]; }
    #pragma unroll
    for (int d = 0; d < 16; ++d) {
        #pragma unroll
        for (int m = 32; m >= 1; m >>= 1) {
            ts[d] += __shfl_xor(ts[d], m);
            tq[d] += __shfl_xor(tq[d], m);
        }
    }
    const int lane = tid & 63, wid = tid >> 6;
    if (lane == 0) {
        #pragma unroll
        for (int d = 0; d < 16; ++d) { sred[wid][d] = ts[d]; sred[wid][16 + d] = tq[d]; }
    }
    __syncthreads();
    if (tid < 32) {
        float tot = sred[0][tid] + sred[1][tid] + sred[2][tid] + sred[3][tid];
        partials[((size_t)s * B + vb) * 64 + tid] = tot;
    }
}

// ---------------- phase conv (gather 16B rows + dot2, no stats) ----------------

template<int COUT, int NPH>
__global__ __launch_bounds__(256)
void convp_kernel(const _Float16* __restrict__ feats,   // [ph][s][(N+1)][8]
                  const int* __restrict__ nb0, const int* __restrict__ nb1,
                  const _Float16* __restrict__ Wt,      // [ph][27][COUT][8]
                  _Float16* __restrict__ part,          // [ph][s][(N+1)][COUT]
                  int N)
{
    constexpr int G = 2 * NPH;
    constexpr int WU4 = KNBR * COUT;      // u4 count per phase
    const int bid = blockIdx.x;
    const int m = bid % G;
    const int s = m / NPH;                // (s,ph) <-> XCD via bid%8
    const int ph = m % NPH;
    const int vb = bid / G;
    const int tid = threadIdx.x;

    __shared__ __align__(16) _Float16 wl[KNBR * COUT * 8];
    for (int i = tid; i < WU4; i += 256)
        ((u4*)wl)[i] = ((const u4*)Wt)[ph * WU4 + i];
    __syncthreads();
    const u4* wp = (const u4*)wl;

    const size_t stride = (size_t)N + 1;
    const _Float16* __restrict__ fs = feats + (size_t)(ph * 2 + s) * stride * 8;
    const int* __restrict__ nbr = s ? nb1 : nb0;
    const int n = vb * 256 + tid;
    const bool act = n < N;

    float acc[COUT];
    #pragma unroll
    for (int d = 0; d < COUT; ++d) acc[d] = 0.f;

    int idx = act ? nbr[(size_t)n * KNBR] : N;
    u4 g = *(const u4*)(fs + (size_t)idx * 8);
    for (int k = 0; k < KNBR; ++k) {
        const int idn = (act && k + 1 < KNBR) ? nbr[(size_t)n * KNBR + k + 1] : idx;
        const u4 gn = *(const u4*)(fs + (size_t)idn * 8);
        #pragma unroll
        for (int d = 0; d < COUT; ++d) {
            const u4 wv = wp[k * COUT + d];
            acc[d] = __builtin_amdgcn_fdot2(bch2(g.x), bch2(wv.x), acc[d], false);
            acc[d] = __builtin_amdgcn_fdot2(bch2(g.y), bch2(wv.y), acc[d], false);
            acc[d] = __builtin_amdgcn_fdot2(bch2(g.z), bch2(wv.z), acc[d], false);
            acc[d] = __builtin_amdgcn_fdot2(bch2(g.w), bch2(wv.w), acc[d], false);
        }
        g = gn; idx = idn;
    }

    if (act) {
        u4* orow = (u4*)(part + ((size_t)(ph * 2 + s) * stride + n) * COUT);
        #pragma unroll
        for (int q = 0; q < COUT / 8; ++q) {
            u4 v = {pkh2(acc[8 * q + 0], acc[8 * q + 1]), pkh2(acc[8 * q + 2], acc[8 * q + 3]),
                    pkh2(acc[8 * q + 4], acc[8 * q + 5]), pkh2(acc[8 * q + 6], acc[8 * q + 7])};
            __builtin_nontemporal_store(v, orow + q);
        }
    }
}

// ---------------- combine phases -> pre-BN rows + BN stat partials ----------------

template<int COUT, int NPH>
__global__ __launch_bounds__(256)
void combine_kernel(const _Float16* __restrict__ part,  // [ph][s][(N+1)][COUT]
                    _Float16* __restrict__ pre,         // [s][(N+1)][COUT]
                    float* __restrict__ partials, int N, int B)
{
    const int bid = blockIdx.x;
    const int s = bid & 1;
    const int vb = bid >> 1;
    const int tid = threadIdx.x;
    const size_t stride = (size_t)N + 1;
    const int n = vb * 256 + tid;
    const bool act = n < N;

    __shared__ float sred[4][64];

    float acc[COUT];
    #pragma unroll
    for (int d = 0; d < COUT; ++d) acc[d] = 0.f;

    if (act) {
        #pragma unroll
        for (int ph = 0; ph < NPH; ++ph) {
            const u4* r = (const u4*)(part + ((size_t)(ph * 2 + s) * stride + n) * COUT);
            #pragma unroll
            for (int q = 0; q < COUT / 8; ++q) {
                const u4 v = __builtin_nontemporal_load(r + q);
                h2 x;
                x = bch2(v.x); acc[8 * q + 0] += (float)x.x; acc[8 * q + 1] += (float)x.y;
                x = bch2(v.y); acc[8 * q + 2] += (float)x.x; acc[8 * q + 3] += (float)x.y;
                x = bch2(v.z); acc[8 * q + 4] += (float)x.x; acc[8 * q + 5] += (float)x.y;
                x = bch2(v.w); acc[8 * q + 6] += (float)x.x; acc[8 * q + 7] += (float)x.y;
            }
        }
        u4* orow = (u4*)(pre + ((size_t)s * stride + n) * COUT);
        #pragma unroll
        for (int q = 0; q < COUT / 8; ++q) {
            u4 v = {pkh2(acc[8 * q + 0], acc[8 * q + 1]), pkh2(acc[8 * q + 2], acc[8 * q + 3]),
                    pkh2(acc[8 * q + 4], acc[8 * q + 5]), pkh2(acc[8 * q + 6], acc[8 * q + 7])};
            __builtin_nontemporal_store(v, orow + q);
        }
    }

    float ts[COUT], tq[COUT];
    #pragma unroll
    for (int d = 0; d < COUT; ++d) { ts[d] = acc[d]; tq[d] = acc[d] * acc[d]; }
    #pragma unroll
    for (int d = 0; d < COUT; ++d) {
        #pragma unroll
        for (int m = 32; m >= 1; m >>= 1) {
            ts[d] += __shfl_xor(ts[d], m);
            tq[d] += __shfl_xor(tq[d], m);
        }
    }
    const int lane = tid & 63, wid = tid >> 6;
    if (lane == 0) {
        #pragma unroll
        for (int d = 0; d < COUT; ++d) { sred[wid][d] = ts[d]; sred[wid][COUT + d] = tq[d]; }
    }
    __syncthreads();
    if (tid < 2 * COUT) {
        float tot = sred[0][tid] + sred[1][tid] + sred[2][tid] + sred[3][tid];
        partials[((size_t)s * B + vb) * 64 + tid] = tot;
    }
}

// ---------------- BN stats -> scale/shift ----------------

template<int COUT>
__global__ __launch_bounds__(256)
void stats_kernel(const float* __restrict__ partials, int B, int N,
                  const float* __restrict__ g, const float* __restrict__ b,
                  float* __restrict__ ss)
{
    const int s = blockIdx.y;
    const int tid = threadIdx.x;
    const float* P = partials + (size_t)s * B * 64;
    const int q = tid & 63;
    const int ch = tid >> 6;
    float a = 0.f;
    for (int i = ch; i < B; i += 4) a += P[(size_t)i * 64 + q];
    __shared__ float red[256];
    red[tid] = a;
    __syncthreads();
    if (tid < 64) red[tid] = red[tid] + red[64 + tid] + red[128 + tid] + red[192 + tid];
    __syncthreads();
    if (tid < COUT) {
        float sum = red[tid];
        float sq = red[COUT + tid];
        float mean = sum / (float)N;
        float var = sq / (float)N - mean * mean;
        float scl = g[tid] * rsqrtf(var + 1e-4f);
        float sft = b[tid] - mean * scl;
        float* ssp = ss + s * 64;
        ssp[tid] = scl;
        ssp[32 + tid] = sft;
    }
}

// ---------------- apply BN+ReLU, write phase-split [ph][s][(N+1)][8] ----------------

template<int COUT>
__global__ __launch_bounds__(256)
void apply_split_kernel(const _Float16* __restrict__ pre, _Float16* __restrict__ post,
                        const float* __restrict__ ss, int N)
{
    constexpr int CH8 = COUT / 8;
    const int s = blockIdx.y;
    const size_t stride = (size_t)N + 1;
    __shared__ float sc[32], sh[32];
    if (threadIdx.x < COUT) {
        sc[threadIdx.x] = ss[s * 64 + threadIdx.x];
        sh[threadIdx.x] = ss[s * 64 + 32 + threadIdx.x];
    }
    __syncthreads();
    const long long chunks = (long long)stride * CH8;
    const long long i = (long long)blockIdx.x * 256 + threadIdx.x;
    if (i >= chunks) return;
    const int row = (int)(i / CH8);
    const int ph = (int)(i % CH8);
    const int cb = ph * 8;
    const u4 v = __builtin_nontemporal_load((const u4*)pre + (size_t)s * stride * CH8 + i);
    u4 r;
    {
        h2 x0 = bch2(v.x), x1 = bch2(v.y), x2 = bch2(v.z), x3 = bch2(v.w);
        r.x = pkh2(bnr((float)x0.x, sc[cb + 0], sh[cb + 0]), bnr((float)x0.y, sc[cb + 1], sh[cb + 1]));
        r.y = pkh2(bnr((float)x1.x, sc[cb + 2], sh[cb + 2]), bnr((float)x1.y, sc[cb + 3], sh[cb + 3]));
        r.z = pkh2(bnr((float)x2.x, sc[cb + 4], sh[cb + 4]), bnr((float)x2.y, sc[cb + 5], sh[cb + 5]));
        r.w = pkh2(bnr((float)x3.x, sc[cb + 6], sh[cb + 6]), bnr((float)x3.y, sc[cb + 7], sh[cb + 7]));
    }
    if (row >= N) r = (u4){0u, 0u, 0u, 0u};
    __builtin_nontemporal_store(r, (u4*)post + (size_t)(ph * 2 + s) * stride + row);
}

// ---------------- point gather + per-batch channel sums (BN3 inline) ----------------

__global__ __launch_bounds__(256)
void pointsum_kernel(const _Float16* __restrict__ h3,  // [s][(N+1)][16] pre-BN fp16
                     const int* __restrict__ id0, const int* __restrict__ id1,
                     const float* __restrict__ ss, float* __restrict__ bsum,
                     int N, int Ppb, int bpb, int bs)
{
    const int bid = blockIdx.x;
    const int s = bid & 1;
    const int pb = bid >> 1;
    const int batch = pb / bpb;
    const int blk = pb % bpb;

    const _Float16* __restrict__ h = h3 + (size_t)s * (N + 1) * 16;
    const int* __restrict__ ids = s ? id1 : id0;

    const float* ssp = ss + s * 64;
    float sc[16], sh[16];
    #pragma unroll
    for (int c = 0; c < 16; ++c) { sc[c] = ssp[c]; sh[c] = ssp[32 + c]; }

    float acc[16];
    #pragma unroll
    for (int c = 0; c < 16; ++c) acc[c] = 0.f;

    const int* bid_p = ids + (size_t)batch * Ppb;
    const int base = blk * (256 * 8) + threadIdx.x;
    for (int i = 0; i < 8; ++i) {
        int off = base + i * 256;
        if (off < Ppb) {
            int vx = __builtin_nontemporal_load(bid_p + off);
            const u4* r = (const u4*)(h + (size_t)vx * 16);
            u4 a = r[0], b = r[1];
            h2 x;
            x = bch2(a.x); acc[0] += bnr((float)x.x, sc[0], sh[0]);   acc[1] += bnr((float)x.y, sc[1], sh[1]);
            x = bch2(a.y); acc[2] += bnr((float)x.x, sc[2], sh[2]);   acc[3] += bnr((float)x.y, sc[3], sh[3]);
            x = bch2(a.z); acc[4] += bnr((float)x.x, sc[4], sh[4]);   acc[5] += bnr((float)x.y, sc[5], sh[5]);
            x = bch2(a.w); acc[6] += bnr((float)x.x, sc[6], sh[6]);   acc[7] += bnr((float)x.y, sc[7], sh[7]);
            x = bch2(b.x); acc[8] += bnr((float)x.x, sc[8], sh[8]);   acc[9] += bnr((float)x.y, sc[9], sh[9]);
            x = bch2(b.y); acc[10] += bnr((float)x.x, sc[10], sh[10]); acc[11] += bnr((float)x.y, sc[11], sh[11]);
            x = bch2(b.z); acc[12] += bnr((float)x.x, sc[12], sh[12]); acc[13] += bnr((float)x.y, sc[13], sh[13]);
            x = bch2(b.w); acc[14] += bnr((float)x.x, sc[14], sh[14]); acc[15] += bnr((float)x.y, sc[15], sh[15]);
        }
    }

    #pragma unroll
    for (int c = 0; c < 16; ++c) {
        #pragma unroll
        for (int m = 32; m >= 1; m >>= 1) acc[c] += __shfl_xor(acc[c], m);
    }
    __shared__ float sred[4][16];
    const int lane = threadIdx.x & 63, wid = threadIdx.x >> 6;
    if (lane == 0) {
        #pragma unroll
        for (int c = 0; c < 16; ++c) sred[wid][c] = acc[c];
    }
    __syncthreads();
    if (threadIdx.x < 16) {
        float tot = sred[0][threadIdx.x] + sred[1][threadIdx.x] + sred[2][threadIdx.x] + sred[3][threadIdx.x];
        atomicAdd(&bsum[((size_t)s * bs + batch) * 16 + threadIdx.x], tot);
    }
}

// ---------------- head ----------------

__global__ void final_kernel(const float* __restrict__ bsum,
                             const float* __restrict__ Wg, const float* __restrict__ bg,
                             const float* __restrict__ Wr, const float* __restrict__ br,
                             float* __restrict__ out, int bs, float invP)
{
    const int t = threadIdx.x;
    const int total = 4 * bs * 3;
    if (t < total) {
        const int x = t % 3;
        const int b = (t / 3) % bs;
        const int r = t / (3 * bs);
        const int s = r & 1;
        const float* W = (r < 2) ? Wg : Wr;
        const float* bias = (r < 2) ? bg : br;
        const float* m = bsum + ((size_t)s * bs + b) * 16;
        float a = bias[x];
        #pragma unroll
        for (int c = 0; c < 16; ++c) a = fmaf(m[c] * invP, W[c * 3 + x], a);
        out[t] = a;
    }
}

// ---------------- launch ----------------

extern "C" void kernel_launch(void* const* d_in, const int* in_sizes, int n_in,
                              void* d_out, int out_size, void* d_ws, size_t ws_size,
                              hipStream_t stream)
{
    (void)n_in; (void)ws_size;
    const float* vf0 = (const float*)d_in[0];
    const int*   nb0 = (const int*)d_in[1];
    const int*   id0 = (const int*)d_in[2];
    const float* vf1 = (const float*)d_in[3];
    const int*   nb1 = (const int*)d_in[4];
    const int*   id1 = (const int*)d_in[5];
    const float* W1 = (const float*)d_in[7];
    const float* g1 = (const float*)d_in[8];
    const float* b1 = (const float*)d_in[9];
    const float* W2 = (const float*)d_in[10];
    const float* g2 = (const float*)d_in[11];
    const float* b2 = (const float*)d_in[12];
    const float* W3 = (const float*)d_in[13];
    const float* g3 = (const float*)d_in[14];
    const float* b3 = (const float*)d_in[15];
    const float* Wg = (const float*)d_in[16];
    const float* bg = (const float*)d_in[17];
    const float* Wr = (const float*)d_in[18];
    const float* br = (const float*)d_in[19];

    const int N = in_sizes[0] / 6;       // 120000
    const int npts = in_sizes[2];        // bs * P
    const int bs = out_size / 12;        // out = [4, bs, 3]
    const int Ppb = npts / bs;
    const size_t stride = (size_t)N + 1;
    const int B = (N + 255) / 256;       // 469 voxel blocks per (s,ph)

    // Arena layout (halves), with lifetime-based reuse:
    //  A  [128*stride]: part2 [2][2][str][32] -> part3 [4][2][str][16]
    //  Bb [ 64*stride]: pre2  [2][str][32]    -> pre3  [2][str][16]
    //  C  [ 64*stride]: fin [2][str][8] + pre1 [2][str][16] -> post2 [4][2][str][8]
    //  D  [ 32*stride]: post1 [2][2][str][8]
    _Float16* A   = (_Float16*)d_ws;
    _Float16* Bb  = A + 128 * stride;
    _Float16* C   = Bb + 64 * stride;
    _Float16* D   = C + 64 * stride;
    _Float16* w1t = D + 32 * stride;                    // 3456
    _Float16* w2t = w1t + KNBR * 16 * 8;                // 13824
    _Float16* w3t = w2t + 2 * KNBR * 32 * 8;            // 13824
    float* partials = (float*)(w3t + 4 * KNBR * 16 * 8);
    float* ssb  = partials + (size_t)2 * B * 64;        // 128
    float* bsum = ssb + 128;                            // 2*bs*16

    _Float16* fin   = C;
    _Float16* pre1  = C + 16 * stride;
    _Float16* post1 = D;
    _Float16* part2 = A;
    _Float16* pre2  = Bb;
    _Float16* post2 = C;
    _Float16* part3 = A;
    _Float16* pre3  = Bb;

    prep_feats_kernel<<<dim3((unsigned)((stride + 255) / 256), 2), 256, 0, stream>>>(vf0, vf1, fin, N);
    prep_weights_kernel<<<4, 256, 0, stream>>>(W1, W2, W3, w1t, w2t, w3t, bsum, 2 * bs * 16);

    // conv1: fin -> pre1 (+stats)
    conv1_kernel<<<2 * B, 256, 0, stream>>>(fin, nb0, nb1, w1t, pre1, partials, N, B);
    stats_kernel<16><<<dim3(1, 2), 256, 0, stream>>>(partials, B, N, g1, b1, ssb);
    apply_split_kernel<16><<<dim3((unsigned)((stride * 2 + 255) / 256), 2), 256, 0, stream>>>(pre1, post1, ssb, N);

    // conv2: post1 (2-phase) -> part2 -> combine -> pre2
    convp_kernel<32, 2><<<4 * B, 256, 0, stream>>>(post1, nb0, nb1, w2t, part2, N);
    combine_kernel<32, 2><<<2 * B, 256, 0, stream>>>(part2, pre2, partials, N, B);
    stats_kernel<32><<<dim3(1, 2), 256, 0, stream>>>(partials, B, N, g2, b2, ssb);
    apply_split_kernel<32><<<dim3((unsigned)((stride * 4 + 255) / 256), 2), 256, 0, stream>>>(pre2, post2, ssb, N);

    // conv3: post2 (4-phase) -> part3 -> combine -> pre3
    convp_kernel<16, 4><<<8 * B, 256, 0, stream>>>(post2, nb0, nb1, w3t, part3, N);
    combine_kernel<16, 4><<<2 * B, 256, 0, stream>>>(part3, pre3, partials, N, B);
    stats_kernel<16><<<dim3(1, 2), 256, 0, stream>>>(partials, B, N, g3, b3, ssb);

    const int bpb = (Ppb + 2047) / 2048;
    pointsum_kernel<<<2 * bpb * bs, 256, 0, stream>>>(pre3, id0, id1, ssb, bsum, N, Ppb, bpb, bs);
    final_kernel<<<1, 64, 0, stream>>>(bsum, Wg, bg, Wr, br, (float*)d_out, bs, 1.0f / Ppb);
}

// Round 6
// 716.631 us; speedup vs baseline: 1.2915x; 1.2915x over previous
//
#include <hip/hip_runtime.h>

// Sparse UNet, fp16, stream-partitioned single-pass gathers.
//  - s=(bid>>2)&1 partition is XCD-pure under chunked round-robin (bid/c)%8
//    for c in {1,2,4} -> each XCD gathers from ONE stream's table only.
//  - conv3 time-phased: two sequential 16-ch half dispatches, each with a
//    1.92MB/XCD gather table (vs 7.68MB single-pass) -> high L2 hit rate.
//  - nt loads for nbr (streaming, don't evict tables); nt stores for outputs;
//    plain cached loads for feature gathers.
//  - BN stats in conv epilogue (or combine); BN+ReLU in streaming apply pass.
//  - head is linear => only per-batch channel sums of h3.

#define DEVI __device__ __forceinline__

typedef _Float16 h2 __attribute__((ext_vector_type(2)));
typedef unsigned u4 __attribute__((ext_vector_type(4)));

constexpr int KNBR = 27;

DEVI h2 bch2(unsigned u) { return __builtin_bit_cast(h2, u); }
DEVI unsigned pkh2(float a, float b) {
    h2 v; v.x = (_Float16)a; v.y = (_Float16)b;
    return __builtin_bit_cast(unsigned, v);
}
DEVI float bnr(float x, float sc, float sh) {
    float y = fmaf(x, sc, sh);
    return y > 0.f ? y : 0.f;
}

// ---------------- prep ----------------

// b0: W1 [k][6][16] -> [k][16][8]
// b1: W2 [k][16][32] -> [k][32][16]
// b2: W3 [k][32][16] -> [h:2][k][16][16]
// b3: zero bsum
__global__ __launch_bounds__(256)
void prep_weights_kernel(const float* __restrict__ W1, const float* __restrict__ W2,
                         const float* __restrict__ W3,
                         _Float16* __restrict__ w1t, _Float16* __restrict__ w2t,
                         _Float16* __restrict__ w3t,
                         float* __restrict__ bsum, int nb)
{
    const int b = blockIdx.x;
    if (b == 3) {
        for (int i = threadIdx.x; i < nb; i += 256) bsum[i] = 0.f;
        return;
    }
    if (b == 0) {
        for (int i = threadIdx.x; i < KNBR * 16 * 8; i += 256) {
            const int c = i % 8, d = (i / 8) % 16, k = i / 128;
            w1t[i] = (_Float16)((c < 6) ? W1[(k * 6 + c) * 16 + d] : 0.f);
        }
    } else if (b == 1) {
        for (int i = threadIdx.x; i < KNBR * 32 * 16; i += 256) {
            const int c = i % 16, d = (i / 16) % 32, k = i / 512;
            w2t[i] = (_Float16)W2[(k * 16 + c) * 32 + d];
        }
    } else {
        for (int i = threadIdx.x; i < 2 * KNBR * 16 * 16; i += 256) {
            const int c = i % 16, d = (i / 16) % 16, k = (i / 256) % KNBR, h = i / (256 * KNBR);
            w3t[i] = (_Float16)W3[(k * 32 + h * 16 + c) * 16 + d];
        }
    }
}

// fp32 [N][6] -> fp16 [s][(N+1)][8] (pad channels, zero row N)
__global__ __launch_bounds__(256)
void prep_feats_kernel(const float* __restrict__ f0, const float* __restrict__ f1,
                       _Float16* __restrict__ o, int N)
{
    const int s = blockIdx.y;
    const float* __restrict__ f = s ? f1 : f0;
    _Float16* __restrict__ out = o + (size_t)s * (N + 1) * 8;
    const int n = blockIdx.x * 256 + threadIdx.x;
    if (n < N) {
        const float2* r = (const float2*)(f + (size_t)n * 6);
        float2 a = r[0], b = r[1], c = r[2];
        u4 w;
        w.x = pkh2(a.x, a.y);
        w.y = pkh2(b.x, b.y);
        w.z = pkh2(c.x, c.y);
        w.w = 0u;
        ((u4*)out)[n] = w;
    } else if (n == N) {
        ((u4*)out)[n] = (u4){0u, 0u, 0u, 0u};
    }
}

// ---------------- generic gather conv ----------------
// feats: [s][(N+1)][CINH], Wt: [27][COUT][CINH], outp: [s][(N+1)][COUT]

template<int C8, int COUT, bool STATS>
__global__ __launch_bounds__(256)
void conv_g(const _Float16* __restrict__ feats,
            const int* __restrict__ nb0, const int* __restrict__ nb1,
            const _Float16* __restrict__ Wt,
            _Float16* __restrict__ outp,
            float* __restrict__ partials, int N, int B)
{
    constexpr int CINH = C8 * 8;
    constexpr int WU4 = KNBR * COUT * C8;
    const int bid = blockIdx.x;
    const int s = (bid >> 2) & 1;            // XCD-robust stream partition
    const int vb = (bid >> 3) * 4 + (bid & 3);
    if (vb >= B) return;
    const int tid = threadIdx.x;

    __shared__ __align__(16) _Float16 wl[KNBR * COUT * CINH];
    __shared__ float sred[4][64];
    for (int i = tid; i < WU4; i += 256)
        ((u4*)wl)[i] = ((const u4*)Wt)[i];
    __syncthreads();
    const u4* wp = (const u4*)wl;

    const size_t stride = (size_t)N + 1;
    const _Float16* __restrict__ fs = feats + (size_t)s * stride * CINH;
    const int* __restrict__ nbr = s ? nb1 : nb0;
    const int n = vb * 256 + tid;
    const bool act = n < N;

    float acc[COUT];
    #pragma unroll
    for (int d = 0; d < COUT; ++d) acc[d] = 0.f;

    int idx = act ? __builtin_nontemporal_load(nbr + (size_t)n * KNBR) : N;
    u4 g[C8];
    {
        const u4* rp = (const u4*)(fs + (size_t)idx * CINH);
        #pragma unroll
        for (int c8 = 0; c8 < C8; ++c8) g[c8] = rp[c8];
    }
    for (int k = 0; k < KNBR; ++k) {
        const int idn = (act && k + 1 < KNBR)
            ? __builtin_nontemporal_load(nbr + (size_t)n * KNBR + k + 1) : idx;
        u4 gn[C8];
        {
            const u4* rp = (const u4*)(fs + (size_t)idn * CINH);
            #pragma unroll
            for (int c8 = 0; c8 < C8; ++c8) gn[c8] = rp[c8];
        }
        #pragma unroll
        for (int d = 0; d < COUT; ++d) {
            #pragma unroll
            for (int c8 = 0; c8 < C8; ++c8) {
                const u4 wv = wp[(k * COUT + d) * C8 + c8];
                acc[d] = __builtin_amdgcn_fdot2(bch2(g[c8].x), bch2(wv.x), acc[d], false);
                acc[d] = __builtin_amdgcn_fdot2(bch2(g[c8].y), bch2(wv.y), acc[d], false);
                acc[d] = __builtin_amdgcn_fdot2(bch2(g[c8].z), bch2(wv.z), acc[d], false);
                acc[d] = __builtin_amdgcn_fdot2(bch2(g[c8].w), bch2(wv.w), acc[d], false);
            }
        }
        #pragma unroll
        for (int c8 = 0; c8 < C8; ++c8) g[c8] = gn[c8];
        idx = idn;
    }

    if (act) {
        u4* orow = (u4*)(outp + ((size_t)s * stride + n) * COUT);
        #pragma unroll
        for (int q = 0; q < COUT / 8; ++q) {
            u4 v = {pkh2(acc[8 * q + 0], acc[8 * q + 1]), pkh2(acc[8 * q + 2], acc[8 * q + 3]),
                    pkh2(acc[8 * q + 4], acc[8 * q + 5]), pkh2(acc[8 * q + 6], acc[8 * q + 7])};
            __builtin_nontemporal_store(v, orow + q);
        }
    }

    if constexpr (STATS) {
        float ts[COUT], tq[COUT];
        #pragma unroll
        for (int d = 0; d < COUT; ++d) { ts[d] = acc[d]; tq[d] = acc[d] * acc[d]; }
        #pragma unroll
        for (int d = 0; d < COUT; ++d) {
            #pragma unroll
            for (int m = 32; m >= 1; m >>= 1) {
                ts[d] += __shfl_xor(ts[d], m);
                tq[d] += __shfl_xor(tq[d], m);
            }
        }
        const int lane = tid & 63, wid = tid >> 6;
        if (lane == 0) {
            #pragma unroll
            for (int d = 0; d < COUT; ++d) { sred[wid][d] = ts[d]; sred[wid][COUT + d] = tq[d]; }
        }
        __syncthreads();
        if (tid < 2 * COUT) {
            float tot = sred[0][tid] + sred[1][tid] + sred[2][tid] + sred[3][tid];
            partials[((size_t)s * B + vb) * 64 + tid] = tot;
        }
    }
}

// ---------------- combine conv3 halves -> pre3 + BN stat partials ----------------

__global__ __launch_bounds__(256)
void combine3_kernel(const _Float16* __restrict__ part,  // [h][s][(N+1)][16]
                     _Float16* __restrict__ pre,         // [s][(N+1)][16]
                     float* __restrict__ partials, int N, int B)
{
    const int bid = blockIdx.x;
    const int s = bid & 1;
    const int vb = bid >> 1;
    const int tid = threadIdx.x;
    const size_t stride = (size_t)N + 1;
    const int n = vb * 256 + tid;
    const bool act = n < N;

    __shared__ float sred[4][64];

    float acc[16];
    #pragma unroll
    for (int d = 0; d < 16; ++d) acc[d] = 0.f;

    if (act) {
        #pragma unroll
        for (int h = 0; h < 2; ++h) {
            const u4* r = (const u4*)(part + ((size_t)(h * 2 + s) * stride + n) * 16);
            #pragma unroll
            for (int q = 0; q < 2; ++q) {
                const u4 v = __builtin_nontemporal_load(r + q);
                h2 x;
                x = bch2(v.x); acc[8 * q + 0] += (float)x.x; acc[8 * q + 1] += (float)x.y;
                x = bch2(v.y); acc[8 * q + 2] += (float)x.x; acc[8 * q + 3] += (float)x.y;
                x = bch2(v.z); acc[8 * q + 4] += (float)x.x; acc[8 * q + 5] += (float)x.y;
                x = bch2(v.w); acc[8 * q + 6] += (float)x.x; acc[8 * q + 7] += (float)x.y;
            }
        }
        u4* orow = (u4*)(pre + ((size_t)s * stride + n) * 16);
        #pragma unroll
        for (int q = 0; q < 2; ++q) {
            u4 v = {pkh2(acc[8 * q + 0], acc[8 * q + 1]), pkh2(acc[8 * q + 2], acc[8 * q + 3]),
                    pkh2(acc[8 * q + 4], acc[8 * q + 5]), pkh2(acc[8 * q + 6], acc[8 * q + 7])};
            __builtin_nontemporal_store(v, orow + q);
        }
    }

    float ts[16], tq[16];
    #pragma unroll
    for (int d = 0; d < 16; ++d) { ts[d] = acc[d]; tq[d] = acc[d] * acc[d]; }
    #pragma unroll
    for (int d = 0; d < 16; ++d) {
        #pragma unroll
        for (int m = 32; m >= 1; m >>= 1) {
            ts[d] += __shfl_xor(ts[d], m);
            tq[d] += __shfl_xor(tq[d], m);
        }
    }
    const int lane = tid & 63, wid = tid >> 6;
    if (lane == 0) {
        #pragma unroll
        for (int d = 0; d < 16; ++d) { sred[wid][d] = ts[d]; sred[wid][16 + d] = tq[d]; }
    }
    __syncthreads();
    if (tid < 32) {
        float tot = sred[0][tid] + sred[1][tid] + sred[2][tid] + sred[3][tid];
        partials[((size_t)s * B + vb) * 64 + tid] = tot;
    }
}

// ---------------- BN stats -> scale/shift ----------------

template<int COUT>
__global__ __launch_bounds__(256)
void stats_kernel(const float* __restrict__ partials, int B, int N,
                  const float* __restrict__ g, const float* __restrict__ b,
                  float* __restrict__ ss)
{
    const int s = blockIdx.y;
    const int tid = threadIdx.x;
    const float* P = partials + (size_t)s * B * 64;
    const int q = tid & 63;
    const int ch = tid >> 6;
    float a = 0.f;
    for (int i = ch; i < B; i += 4) a += P[(size_t)i * 64 + q];
    __shared__ float red[256];
    red[tid] = a;
    __syncthreads();
    if (tid < 64) red[tid] = red[tid] + red[64 + tid] + red[128 + tid] + red[192 + tid];
    __syncthreads();
    if (tid < COUT) {
        float sum = red[tid];
        float sq = red[COUT + tid];
        float mean = sum / (float)N;
        float var = sq / (float)N - mean * mean;
        float scl = g[tid] * rsqrtf(var + 1e-4f);
        float sft = b[tid] - mean * scl;
        float* ssp = ss + s * 64;
        ssp[tid] = scl;
        ssp[32 + tid] = sft;
    }
}

// ---------------- apply BN+ReLU (streaming); SPLIT: 32ch -> two 16ch tables ----------------

template<int COUT, bool SPLIT>
__global__ __launch_bounds__(256)
void apply_kernel(const _Float16* __restrict__ pre, _Float16* __restrict__ post,
                  const float* __restrict__ ss, int N)
{
    constexpr int CH8 = COUT / 8;
    const int s = blockIdx.y;
    const size_t stride = (size_t)N + 1;
    __shared__ float sc[32], sh[32];
    if (threadIdx.x < COUT) {
        sc[threadIdx.x] = ss[s * 64 + threadIdx.x];
        sh[threadIdx.x] = ss[s * 64 + 32 + threadIdx.x];
    }
    __syncthreads();
    const long long chunks = (long long)stride * CH8;
    const long long i = (long long)blockIdx.x * 256 + threadIdx.x;
    if (i >= chunks) return;
    const int row = (int)(i / CH8);
    const int ph8 = (int)(i % CH8);
    const int cb = ph8 * 8;
    const u4 v = __builtin_nontemporal_load((const u4*)pre + (size_t)s * stride * CH8 + i);
    u4 r;
    {
        h2 x0 = bch2(v.x), x1 = bch2(v.y), x2 = bch2(v.z), x3 = bch2(v.w);
        r.x = pkh2(bnr((float)x0.x, sc[cb + 0], sh[cb + 0]), bnr((float)x0.y, sc[cb + 1], sh[cb + 1]));
        r.y = pkh2(bnr((float)x1.x, sc[cb + 2], sh[cb + 2]), bnr((float)x1.y, sc[cb + 3], sh[cb + 3]));
        r.z = pkh2(bnr((float)x2.x, sc[cb + 4], sh[cb + 4]), bnr((float)x2.y, sc[cb + 5], sh[cb + 5]));
        r.w = pkh2(bnr((float)x3.x, sc[cb + 6], sh[cb + 6]), bnr((float)x3.y, sc[cb + 7], sh[cb + 7]));
    }
    if (row >= N) r = (u4){0u, 0u, 0u, 0u};
    size_t dsti;
    if constexpr (SPLIT) {
        const int h = ph8 >> 1;
        const int col8 = ph8 & 1;
        dsti = ((size_t)(h * 2 + s) * stride + row) * 2 + col8;   // [h][s][str][16]
    } else {
        dsti = (size_t)s * stride * CH8 + i;
    }
    __builtin_nontemporal_store(r, (u4*)post + dsti);
}

// ---------------- point gather + per-batch channel sums (BN3 inline) ----------------

__global__ __launch_bounds__(256)
void pointsum_kernel(const _Float16* __restrict__ h3,  // [s][(N+1)][16] pre-BN fp16
                     const int* __restrict__ id0, const int* __restrict__ id1,
                     const float* __restrict__ ss, float* __restrict__ bsum,
                     int N, int Ppb, int bpb, int bs, int PB)
{
    const int bid = blockIdx.x;
    const int s = (bid >> 2) & 1;
    const int pb = (bid >> 3) * 4 + (bid & 3);
    if (pb >= PB) return;
    const int batch = pb / bpb;
    const int blk = pb % bpb;

    const _Float16* __restrict__ h = h3 + (size_t)s * (N + 1) * 16;
    const int* __restrict__ ids = s ? id1 : id0;

    const float* ssp = ss + s * 64;
    float sc[16], sh[16];
    #pragma unroll
    for (int c = 0; c < 16; ++c) { sc[c] = ssp[c]; sh[c] = ssp[32 + c]; }

    float acc[16];
    #pragma unroll
    for (int c = 0; c < 16; ++c) acc[c] = 0.f;

    const int* bid_p = ids + (size_t)batch * Ppb;
    const int base = blk * (256 * 8) + threadIdx.x;
    for (int i = 0; i < 8; ++i) {
        int off = base + i * 256;
        if (off < Ppb) {
            int vx = __builtin_nontemporal_load(bid_p + off);
            const u4* r = (const u4*)(h + (size_t)vx * 16);
            u4 a = r[0], b = r[1];
            h2 x;
            x = bch2(a.x); acc[0] += bnr((float)x.x, sc[0], sh[0]);   acc[1] += bnr((float)x.y, sc[1], sh[1]);
            x = bch2(a.y); acc[2] += bnr((float)x.x, sc[2], sh[2]);   acc[3] += bnr((float)x.y, sc[3], sh[3]);
            x = bch2(a.z); acc[4] += bnr((float)x.x, sc[4], sh[4]);   acc[5] += bnr((float)x.y, sc[5], sh[5]);
            x = bch2(a.w); acc[6] += bnr((float)x.x, sc[6], sh[6]);   acc[7] += bnr((float)x.y, sc[7], sh[7]);
            x = bch2(b.x); acc[8] += bnr((float)x.x, sc[8], sh[8]);   acc[9] += bnr((float)x.y, sc[9], sh[9]);
            x = bch2(b.y); acc[10] += bnr((float)x.x, sc[10], sh[10]); acc[11] += bnr((float)x.y, sc[11], sh[11]);
            x = bch2(b.z); acc[12] += bnr((float)x.x, sc[12], sh[12]); acc[13] += bnr((float)x.y, sc[13], sh[13]);
            x = bch2(b.w); acc[14] += bnr((float)x.x, sc[14], sh[14]); acc[15] += bnr((float)x.y, sc[15], sh[15]);
        }
    }

    #pragma unroll
    for (int c = 0; c < 16; ++c) {
        #pragma unroll
        for (int m = 32; m >= 1; m >>= 1) acc[c] += __shfl_xor(acc[c], m);
    }
    __shared__ float sred[4][16];
    const int lane = threadIdx.x & 63, wid = threadIdx.x >> 6;
    if (lane == 0) {
        #pragma unroll
        for (int c = 0; c < 16; ++c) sred[wid][c] = acc[c];
    }
    __syncthreads();
    if (threadIdx.x < 16) {
        float tot = sred[0][threadIdx.x] + sred[1][threadIdx.x] + sred[2][threadIdx.x] + sred[3][threadIdx.x];
        atomicAdd(&bsum[((size_t)s * bs + batch) * 16 + threadIdx.x], tot);
    }
}

// ---------------- head ----------------

__global__ void final_kernel(const float* __restrict__ bsum,
                             const float* __restrict__ Wg, const float* __restrict__ bg,
                             const float* __restrict__ Wr, const float* __restrict__ br,
                             float* __restrict__ out, int bs, float invP)
{
    const int t = threadIdx.x;
    const int total = 4 * bs * 3;
    if (t < total) {
        const int x = t % 3;
        const int b = (t / 3) % bs;
        const int r = t / (3 * bs);
        const int s = r & 1;
        const float* W = (r < 2) ? Wg : Wr;
        const float* bias = (r < 2) ? bg : br;
        const float* m = bsum + ((size_t)s * bs + b) * 16;
        float a = bias[x];
        #pragma unroll
        for (int c = 0; c < 16; ++c) a = fmaf(m[c] * invP, W[c * 3 + x], a);
        out[t] = a;
    }
}

// ---------------- launch ----------------

extern "C" void kernel_launch(void* const* d_in, const int* in_sizes, int n_in,
                              void* d_out, int out_size, void* d_ws, size_t ws_size,
                              hipStream_t stream)
{
    (void)n_in; (void)ws_size;
    const float* vf0 = (const float*)d_in[0];
    const int*   nb0 = (const int*)d_in[1];
    const int*   id0 = (const int*)d_in[2];
    const float* vf1 = (const float*)d_in[3];
    const int*   nb1 = (const int*)d_in[4];
    const int*   id1 = (const int*)d_in[5];
    const float* W1 = (const float*)d_in[7];
    const float* g1 = (const float*)d_in[8];
    const float* b1 = (const float*)d_in[9];
    const float* W2 = (const float*)d_in[10];
    const float* g2 = (const float*)d_in[11];
    const float* b2 = (const float*)d_in[12];
    const float* W3 = (const float*)d_in[13];
    const float* g3 = (const float*)d_in[14];
    const float* b3 = (const float*)d_in[15];
    const float* Wg = (const float*)d_in[16];
    const float* bg = (const float*)d_in[17];
    const float* Wr = (const float*)d_in[18];
    const float* br = (const float*)d_in[19];

    const int N = in_sizes[0] / 6;       // 120000
    const int npts = in_sizes[2];        // bs * P
    const int bs = out_size / 12;        // out = [4, bs, 3]
    const int Ppb = npts / bs;
    const size_t stride = (size_t)N + 1;
    const int B = (N + 255) / 256;
    const int B4 = ((B + 3) / 4) * 4;

    // Arena layout (halves), lifetime reuse:
    //  A  [64*str]: pre2 [s][str][32]            -> pre3 [s][str][16]
    //  Bv [64*str]: fin [s][str][8] + pre1 [s][str][16] -> post2 halves [h][s][str][16]
    //  C  [64*str]: post1 [s][str][16]           -> part3 [h][s][str][16]
    _Float16* A   = (_Float16*)d_ws;
    _Float16* Bv  = A + 64 * stride;
    _Float16* C   = Bv + 64 * stride;
    _Float16* w1t = C + 64 * stride;                    // 3456
    _Float16* w2t = w1t + KNBR * 16 * 8;                // 13824
    _Float16* w3t = w2t + KNBR * 32 * 16;               // 13824
    float* partials = (float*)(w3t + 2 * KNBR * 16 * 16);  // 2*B*64
    float* ssb  = partials + (size_t)2 * B * 64;        // 128
    float* bsum = ssb + 128;                            // 2*bs*16

    _Float16* fin    = Bv;
    _Float16* pre1   = Bv + 16 * stride;
    _Float16* post1  = C;
    _Float16* pre2   = A;
    _Float16* post2h = Bv;          // [h][s][str][16]
    _Float16* part3  = C;           // [h][s][str][16]
    _Float16* pre3   = A;

    prep_feats_kernel<<<dim3((unsigned)((stride + 255) / 256), 2), 256, 0, stream>>>(vf0, vf1, fin, N);
    prep_weights_kernel<<<4, 256, 0, stream>>>(W1, W2, W3, w1t, w2t, w3t, bsum, 2 * bs * 16);

    // conv1: fin -> pre1 (+stats)
    conv_g<1, 16, true><<<2 * B4, 256, 0, stream>>>(fin, nb0, nb1, w1t, pre1, partials, N, B);
    stats_kernel<16><<<dim3(1, 2), 256, 0, stream>>>(partials, B, N, g1, b1, ssb);
    apply_kernel<16, false><<<dim3((unsigned)((stride * 2 + 255) / 256), 2), 256, 0, stream>>>(pre1, post1, ssb, N);

    // conv2: post1 -> pre2 (+stats)
    conv_g<2, 32, true><<<2 * B4, 256, 0, stream>>>(post1, nb0, nb1, w2t, pre2, partials, N, B);
    stats_kernel<32><<<dim3(1, 2), 256, 0, stream>>>(partials, B, N, g2, b2, ssb);
    apply_kernel<32, true><<<dim3((unsigned)((stride * 4 + 255) / 256), 2), 256, 0, stream>>>(pre2, post2h, ssb, N);

    // conv3: two time-phased half dispatches, then combine (+stats)
    conv_g<2, 16, false><<<2 * B4, 256, 0, stream>>>(
        post2h, nb0, nb1, w3t, part3, nullptr, N, B);
    conv_g<2, 16, false><<<2 * B4, 256, 0, stream>>>(
        post2h + 2 * stride * 16, nb0, nb1, w3t + KNBR * 16 * 16, part3 + 2 * stride * 16, nullptr, N, B);
    combine3_kernel<<<2 * B, 256, 0, stream>>>(part3, pre3, partials, N, B);
    stats_kernel<16><<<dim3(1, 2), 256, 0, stream>>>(partials, B, N, g3, b3, ssb);

    const int bpb = (Ppb + 2047) / 2048;
    const int PB = bpb * bs;
    const int PB4 = ((PB + 3) / 4) * 4;
    pointsum_kernel<<<2 * PB4, 256, 0, stream>>>(pre3, id0, id1, ssb, bsum, N, Ppb, bpb, bs, PB);
    final_kernel<<<1, 64, 0, stream>>>(bsum, Wg, bg, Wr, br, (float*)d_out, bs, 1.0f / Ppb);
}